// Round 2
// baseline (232.573 us; speedup 1.0000x reference)
//
#include <hip/hip_runtime.h>

// MeanPool v2: balanced chunked segment-sum with atomics.
//   x [N=1e6, 256] f32, batch [N] sorted int32, out [G=1024, 256] f32.
// Phase 0: memset out (sums) and ws (counts) to zero.
// Phase 1: 128-row chunks, 4 teams x 64 lanes x 32 rows each; teams stream
//          rows, detect graph boundaries inline from sorted batch values,
//          flush float4 partials via device-scope f32 atomic adds.
// Phase 2: out[g] /= max(count[g], 1).

#define CHUNK 128   // rows per block
#define TCH   32    // rows per 64-lane team

__device__ __forceinline__ float4 f4add(float4 a, float4 b) {
    return make_float4(a.x + b.x, a.y + b.y, a.z + b.z, a.w + b.w);
}

__device__ __forceinline__ void atomAddF(float* p, float v) {
    // Always-available builtin; lowers to global_atomic_add_f32 on gfx950.
    __hip_atomic_fetch_add(p, v, __ATOMIC_RELAXED, __HIP_MEMORY_SCOPE_AGENT);
}

__device__ __forceinline__ void flush_seg(float* __restrict__ out,
                                          int* __restrict__ cnt,
                                          int g, int q, float4 a, int len) {
    float* p = out + (size_t)g * 256 + q * 4;
    atomAddF(p + 0, a.x);
    atomAddF(p + 1, a.y);
    atomAddF(p + 2, a.z);
    atomAddF(p + 3, a.w);
    if (q == 0) atomicAdd(cnt + g, len);
}

__global__ __launch_bounds__(256) void meanpool_phase1(
    const float* __restrict__ x,
    const int* __restrict__ batch,
    float* __restrict__ out,
    int* __restrict__ cnt,
    int N)
{
    const int q = threadIdx.x & 63;   // float4 column within the 256-f row
    const int r = threadIdx.x >> 6;   // team 0..3

    int i = blockIdx.x * CHUNK + r * TCH;
    if (i >= N) return;
    const int e = min(N, i + TCH);

    const float4* __restrict__ xv = reinterpret_cast<const float4*>(x);

    float4 acc = make_float4(0.f, 0.f, 0.f, 0.f);
    int cg = batch[i];        // current graph id (uniform across the wave)
    int segStart = i;

    while (i < e) {
        if (i + 4 <= e) {
            const int b0 = batch[i], b1 = batch[i + 1];
            const int b2 = batch[i + 2], b3 = batch[i + 3];
            if (b0 == cg && b1 == cg && b2 == cg && b3 == cg) {
                float4 v0 = xv[(size_t)(i    ) * 64 + q];
                float4 v1 = xv[(size_t)(i + 1) * 64 + q];
                float4 v2 = xv[(size_t)(i + 2) * 64 + q];
                float4 v3 = xv[(size_t)(i + 3) * 64 + q];
                acc = f4add(acc, f4add(f4add(v0, v1), f4add(v2, v3)));
                i += 4;
                continue;
            }
        }
        // boundary region: one row at a time
        const int b = batch[i];
        if (b != cg) {
            flush_seg(out, cnt, cg, q, acc, i - segStart);
            acc = make_float4(0.f, 0.f, 0.f, 0.f);
            cg = b;
            segStart = i;
        }
        acc = f4add(acc, xv[(size_t)i * 64 + q]);
        ++i;
    }
    flush_seg(out, cnt, cg, q, acc, i - segStart);
}

__global__ __launch_bounds__(64) void meanpool_phase2(
    float* __restrict__ out,
    const int* __restrict__ cnt)
{
    const int g = blockIdx.x;
    const int q = threadIdx.x;            // 64 lanes = 64 float4 columns
    const int c = cnt[g];
    const float inv = 1.0f / (float)(c > 1 ? c : 1);
    float4* ov = reinterpret_cast<float4*>(out);
    float4 v = ov[(size_t)g * 64 + q];
    ov[(size_t)g * 64 + q] =
        make_float4(v.x * inv, v.y * inv, v.z * inv, v.w * inv);
}

extern "C" void kernel_launch(void* const* d_in, const int* in_sizes, int n_in,
                              void* d_out, int out_size, void* d_ws, size_t ws_size,
                              hipStream_t stream) {
    const float* x     = (const float*)d_in[0];
    const int*   batch = (const int*)d_in[1];
    float*       out   = (float*)d_out;
    int*         cnt   = (int*)d_ws;

    const int N = in_sizes[1];        // nodes (1,000,000)
    const int G = out_size / 256;     // graphs (1024)
    const int NB = (N + CHUNK - 1) / CHUNK;

    hipMemsetAsync(out, 0, (size_t)out_size * sizeof(float), stream);
    hipMemsetAsync(cnt, 0, (size_t)G * sizeof(int), stream);

    meanpool_phase1<<<NB, 256, 0, stream>>>(x, batch, out, cnt, N);
    meanpool_phase2<<<G, 64, 0, stream>>>(out, cnt);
}

// Round 3
// 194.799 us; speedup vs baseline: 1.1939x; 1.1939x over previous
//
#include <hip/hip_runtime.h>

// MeanPool v3: fixed 512-row chunks, LDS-hoisted boundary detection,
// v1-style deep-unrolled float4 streaming per sub-segment, block-level
// LDS reduction before atomic flush (0.76M atomics vs v2's 8M).
//   x [N=1e6, 256] f32, batch [N] sorted int32, out [G=1024, 256] f32.

#define CHUNK 512
#define MAXB  16

__device__ __forceinline__ float4 f4add(float4 a, float4 b) {
    return make_float4(a.x + b.x, a.y + b.y, a.z + b.z, a.w + b.w);
}

__device__ __forceinline__ void atomAddF(float* p, float v) {
    __hip_atomic_fetch_add(p, v, __ATOMIC_RELAXED, __HIP_MEMORY_SCOPE_AGENT);
}

__global__ __launch_bounds__(256, 8) void meanpool_phase1(
    const float* __restrict__ x,
    const int* __restrict__ batch,
    float* __restrict__ out,
    int* __restrict__ cnt,
    int N)
{
    const int tid = threadIdx.x;
    const int q = tid & 63;          // float4 column 0..63
    const int r = tid >> 6;          // team 0..3
    const int B = blockIdx.x * CHUNK;
    const int E = min(N, B + CHUNK);
    const int L = E - B;

    __shared__ int    s_batch[CHUNK];
    __shared__ int    s_nb;
    __shared__ int    s_bpos[MAXB];
    __shared__ float4 s_part[3][64];

    // --- stage batch window into LDS (coalesced) ---
    for (int p = tid; p < L; p += 256) s_batch[p] = batch[B + p];
    if (tid == 0) s_nb = 0;
    __syncthreads();

    // --- parallel boundary detection (segment starts within window) ---
    for (int p = tid; p < L; p += 256) {
        bool bd = (p == 0) || (s_batch[p] != s_batch[p - 1]);
        if (bd) {
            int k = atomicAdd(&s_nb, 1);
            if (k < MAXB) s_bpos[k] = p;
        }
    }
    __syncthreads();
    const int nb = s_nb;

    const float4* __restrict__ xv = reinterpret_cast<const float4*>(x);

    if (nb <= MAXB) {
        if (tid == 0 && nb > 1) {
            // insertion sort of boundary positions (nb is 1-3 in practice)
            for (int a = 1; a < nb; ++a) {
                int v = s_bpos[a]; int b = a - 1;
                while (b >= 0 && s_bpos[b] > v) { s_bpos[b + 1] = s_bpos[b]; --b; }
                s_bpos[b + 1] = v;
            }
        }
        __syncthreads();

        for (int k = 0; k < nb; ++k) {
            const int s = B + s_bpos[k];
            const int e = (k + 1 < nb) ? (B + s_bpos[k + 1]) : E;
            const int g = s_batch[s - B];

            // v1-style stream: team r owns rows ≡ r (mod 4), 4-deep unroll
            float4 a0 = make_float4(0.f, 0.f, 0.f, 0.f);
            float4 a1 = a0, a2 = a0, a3 = a0;
            int i = s + r;
            for (; i + 12 < e; i += 16) {
                a0 = f4add(a0, xv[(size_t)(i     ) * 64 + q]);
                a1 = f4add(a1, xv[(size_t)(i +  4) * 64 + q]);
                a2 = f4add(a2, xv[(size_t)(i +  8) * 64 + q]);
                a3 = f4add(a3, xv[(size_t)(i + 12) * 64 + q]);
            }
            for (; i < e; i += 4) a0 = f4add(a0, xv[(size_t)i * 64 + q]);
            a0 = f4add(f4add(a0, a1), f4add(a2, a3));

            // block-level reduction, then one atomic flush per sub-segment
            if (r > 0) s_part[r - 1][q] = a0;
            __syncthreads();
            if (r == 0) {
                a0 = f4add(a0, s_part[0][q]);
                a0 = f4add(a0, s_part[1][q]);
                a0 = f4add(a0, s_part[2][q]);
                float* p = out + (size_t)g * 256 + q * 4;
                atomAddF(p + 0, a0.x);
                atomAddF(p + 1, a0.y);
                atomAddF(p + 2, a0.z);
                atomAddF(p + 3, a0.w);
                if (q == 0) atomicAdd(cnt + g, e - s);
            }
            __syncthreads();   // s_part reused next iteration
        }
    } else {
        // pathological fallback (never hit for this input): row-at-a-time
        if (r == 0) {
            for (int i = B; i < E; ++i) {
                const int g = s_batch[i - B];
                float4 v = xv[(size_t)i * 64 + q];
                float* p = out + (size_t)g * 256 + q * 4;
                atomAddF(p + 0, v.x);
                atomAddF(p + 1, v.y);
                atomAddF(p + 2, v.z);
                atomAddF(p + 3, v.w);
                if (q == 0) atomicAdd(cnt + g, 1);
            }
        }
    }
}

__global__ __launch_bounds__(64) void meanpool_phase2(
    float* __restrict__ out,
    const int* __restrict__ cnt)
{
    const int g = blockIdx.x;
    const int q = threadIdx.x;
    const int c = cnt[g];
    const float inv = 1.0f / (float)(c > 1 ? c : 1);
    float4* ov = reinterpret_cast<float4*>(out);
    float4 v = ov[(size_t)g * 64 + q];
    ov[(size_t)g * 64 + q] =
        make_float4(v.x * inv, v.y * inv, v.z * inv, v.w * inv);
}

extern "C" void kernel_launch(void* const* d_in, const int* in_sizes, int n_in,
                              void* d_out, int out_size, void* d_ws, size_t ws_size,
                              hipStream_t stream) {
    const float* x     = (const float*)d_in[0];
    const int*   batch = (const int*)d_in[1];
    float*       out   = (float*)d_out;
    int*         cnt   = (int*)d_ws;

    const int N = in_sizes[1];        // nodes (1,000,000)
    const int G = out_size / 256;     // graphs (1024)
    const int NB = (N + CHUNK - 1) / CHUNK;

    hipMemsetAsync(out, 0, (size_t)out_size * sizeof(float), stream);
    hipMemsetAsync(cnt, 0, (size_t)G * sizeof(int), stream);

    meanpool_phase1<<<NB, 256, 0, stream>>>(x, batch, out, cnt, N);
    meanpool_phase2<<<G, 64, 0, stream>>>(out, cnt);
}

// Round 4
// 192.746 us; speedup vs baseline: 1.2066x; 1.0107x over previous
//
#include <hip/hip_runtime.h>

// MeanPool v4: atomic-free, memset-free 3-kernel pipeline.
//   A: bounds[g] = lower_bound(batch, g) for g in [0, G]   (1025 searches)
//   B: 4096 quarter-graph blocks -> partial sums in ws (waterfall-balanced)
//   C: out[g] = (sum of 4 quarter partials) / max(count, 1)
// Fallback to v1 single-kernel if ws_size is too small.

__device__ __forceinline__ float4 f4add(float4 a, float4 b) {
    return make_float4(a.x + b.x, a.y + b.y, a.z + b.z, a.w + b.w);
}

// ---------- A: segment bounds ----------
__global__ __launch_bounds__(256) void bounds_kernel(
    const int* __restrict__ batch, int* __restrict__ bounds, int N, int G)
{
    const int g = blockIdx.x * 256 + threadIdx.x;
    if (g > G) return;
    int lo = 0, hi = N;
    while (lo < hi) {
        int mid = (lo + hi) >> 1;
        if (batch[mid] < g) lo = mid + 1; else hi = mid;
    }
    bounds[g] = lo;   // bounds[G] == N (all values < G)
}

// ---------- B: quarter-graph partial sums ----------
__global__ __launch_bounds__(256) void quarter_sum_kernel(
    const float* __restrict__ x, const int* __restrict__ bounds,
    float* __restrict__ partial)
{
    const int g  = blockIdx.x >> 2;
    const int qt = blockIdx.x & 3;
    const int s0 = bounds[g];
    const int e0 = bounds[g + 1];
    const int len = e0 - s0;
    const int qs = s0 + (int)(((long long)len * qt)       >> 2);
    const int qe = s0 + (int)(((long long)len * (qt + 1)) >> 2);

    const int q = threadIdx.x & 63;   // float4 column 0..63
    const int r = threadIdx.x >> 6;   // team 0..3
    const float4* __restrict__ xv = reinterpret_cast<const float4*>(x);

    // v1-proven stream: 4 teams x 4 independent accumulators (16 rows/iter)
    float4 a0 = make_float4(0.f, 0.f, 0.f, 0.f);
    float4 a1 = a0, a2 = a0, a3 = a0;
    int i = qs + r;
    for (; i + 12 < qe; i += 16) {
        a0 = f4add(a0, xv[(size_t)(i     ) * 64 + q]);
        a1 = f4add(a1, xv[(size_t)(i +  4) * 64 + q]);
        a2 = f4add(a2, xv[(size_t)(i +  8) * 64 + q]);
        a3 = f4add(a3, xv[(size_t)(i + 12) * 64 + q]);
    }
    for (; i < qe; i += 4) a0 = f4add(a0, xv[(size_t)i * 64 + q]);
    a0 = f4add(f4add(a0, a1), f4add(a2, a3));

    __shared__ float4 s_part[3][64];
    if (r > 0) s_part[r - 1][q] = a0;
    __syncthreads();
    if (r == 0) {
        a0 = f4add(a0, s_part[0][q]);
        a0 = f4add(a0, s_part[1][q]);
        a0 = f4add(a0, s_part[2][q]);
        reinterpret_cast<float4*>(partial)[(size_t)blockIdx.x * 64 + q] = a0;
    }
}

// ---------- C: combine quarters + divide ----------
__global__ __launch_bounds__(64) void combine_kernel(
    const float* __restrict__ partial, const int* __restrict__ bounds,
    float* __restrict__ out)
{
    const int g = blockIdx.x;
    const int q = threadIdx.x;
    const float4* __restrict__ pv = reinterpret_cast<const float4*>(partial);
    float4 a =        pv[(size_t)(4 * g    ) * 64 + q];
    a = f4add(a,      pv[(size_t)(4 * g + 1) * 64 + q]);
    a = f4add(a,      pv[(size_t)(4 * g + 2) * 64 + q]);
    a = f4add(a,      pv[(size_t)(4 * g + 3) * 64 + q]);
    const int len = bounds[g + 1] - bounds[g];
    const float inv = 1.0f / (float)(len > 1 ? len : 1);
    reinterpret_cast<float4*>(out)[(size_t)g * 64 + q] =
        make_float4(a.x * inv, a.y * inv, a.z * inv, a.w * inv);
}

// ---------- fallback: proven v1 (184 us) ----------
__global__ __launch_bounds__(256) void meanpool_v1(
    const float* __restrict__ x, const int* __restrict__ batch,
    float* __restrict__ out, int N)
{
    const int g = blockIdx.x;
    __shared__ int s_b[2];
    if (threadIdx.x < 2) {
        const int target = g + (int)threadIdx.x;
        int lo = 0, hi = N;
        while (lo < hi) {
            int mid = (lo + hi) >> 1;
            if (batch[mid] < target) lo = mid + 1; else hi = mid;
        }
        s_b[threadIdx.x] = lo;
    }
    __syncthreads();
    const int start = s_b[0];
    const int end   = s_b[1];
    const int count = end - start;

    const int q = threadIdx.x & 63;
    const int r = threadIdx.x >> 6;
    const float4* __restrict__ xv = reinterpret_cast<const float4*>(x);

    float4 a0 = make_float4(0.f, 0.f, 0.f, 0.f);
    float4 a1 = a0, a2 = a0, a3 = a0;
    int i = start + r;
    for (; i + 12 < end; i += 16) {
        a0 = f4add(a0, xv[(size_t)(i     ) * 64 + q]);
        a1 = f4add(a1, xv[(size_t)(i +  4) * 64 + q]);
        a2 = f4add(a2, xv[(size_t)(i +  8) * 64 + q]);
        a3 = f4add(a3, xv[(size_t)(i + 12) * 64 + q]);
    }
    for (; i < end; i += 4) a0 = f4add(a0, xv[(size_t)i * 64 + q]);
    a0 = f4add(f4add(a0, a1), f4add(a2, a3));

    __shared__ float4 s_part[3][64];
    if (r > 0) s_part[r - 1][q] = a0;
    __syncthreads();
    if (r == 0) {
        a0 = f4add(a0, s_part[0][q]);
        a0 = f4add(a0, s_part[1][q]);
        a0 = f4add(a0, s_part[2][q]);
        const float inv = 1.0f / (float)(count > 1 ? count : 1);
        reinterpret_cast<float4*>(out)[(size_t)g * 64 + q] =
            make_float4(a0.x * inv, a0.y * inv, a0.z * inv, a0.w * inv);
    }
}

extern "C" void kernel_launch(void* const* d_in, const int* in_sizes, int n_in,
                              void* d_out, int out_size, void* d_ws, size_t ws_size,
                              hipStream_t stream) {
    const float* x     = (const float*)d_in[0];
    const int*   batch = (const int*)d_in[1];
    float*       out   = (float*)d_out;

    const int N = in_sizes[1];        // nodes (1,000,000)
    const int G = out_size / 256;     // graphs (1024)

    const size_t partial_bytes = (size_t)G * 4 * 256 * sizeof(float); // 4 MB
    const size_t bounds_bytes  = (size_t)(G + 1) * sizeof(int);
    if (ws_size < partial_bytes + bounds_bytes) {
        meanpool_v1<<<G, 256, 0, stream>>>(x, batch, out, N);
        return;
    }

    float* partial = (float*)d_ws;
    int*   bounds  = (int*)((char*)d_ws + partial_bytes);

    bounds_kernel<<<(G + 256) / 256, 256, 0, stream>>>(batch, bounds, N, G);
    quarter_sum_kernel<<<G * 4, 256, 0, stream>>>(x, bounds, partial);
    combine_kernel<<<G, 64, 0, stream>>>(partial, bounds, out);
}

// Round 5
// 156.922 us; speedup vs baseline: 1.4821x; 1.2283x over previous
//
#include <hip/hip_runtime.h>

// MeanPool v5: v1's proven graph-per-block structure (1024 blocks x 256 thr,
// 4 teams x 4-deep float4 stream), with two micro-opts:
//   1. non-temporal loads for x (read-once stream, skip L2 allocation)
//   2. interpolation-bracketed segment search (batch ~uniform: probe at
//      g*N/G, gallop, short binary) instead of full 20-probe binary search.
// Hot loop otherwise byte-identical to the 184 us v1.

typedef float vf4 __attribute__((ext_vector_type(4)));

__global__ __launch_bounds__(256) void meanpool_v5(
    const float* __restrict__ x,
    const int* __restrict__ batch,
    float* __restrict__ out,
    int N, int G)
{
    const int g = blockIdx.x;

    // --- segment bounds: interpolation bracket + gallop + binary ---
    __shared__ int s_b[2];
    if (threadIdx.x < 2) {
        const int target = g + (int)threadIdx.x;   // lower_bound(target)
        int lo = 0, hi = N;
        if (target <= 0) {
            lo = 0;                      // batch values are >= 0
        } else if (target >= G) {
            lo = N;                      // batch values are < G
        } else {
            int p = (int)(((long long)target * N) / G);
            p = min(p, N - 1);
            if (batch[p] < target) {
                lo = p + 1;
                int s = 512;
                while (lo + s <= N && batch[lo + s - 1] < target) {
                    lo += s; s <<= 1;
                }
                hi = min(N, lo + s);
            } else {
                hi = p;
                int s = 512;
                while (hi - s >= 0 && batch[hi - s] >= target) {
                    hi -= s; s <<= 1;
                }
                lo = max(0, hi - s);
            }
            while (lo < hi) {
                int mid = (lo + hi) >> 1;
                if (batch[mid] < target) lo = mid + 1; else hi = mid;
            }
        }
        s_b[threadIdx.x] = lo;
    }
    __syncthreads();
    const int start = s_b[0];
    const int end   = s_b[1];
    const int count = end - start;

    // --- streaming sum: 4 teams (r) x 64 lanes (q), nt float4 loads ---
    const int q = threadIdx.x & 63;   // float4 column within the 256-f row
    const int r = threadIdx.x >> 6;   // team 0..3
    const vf4* __restrict__ xv = reinterpret_cast<const vf4*>(x);

    vf4 a0 = (vf4)0.0f, a1 = (vf4)0.0f, a2 = (vf4)0.0f, a3 = (vf4)0.0f;

    int i = start + r;
    for (; i + 12 < end; i += 16) {
        a0 += __builtin_nontemporal_load(xv + (size_t)(i     ) * 64 + q);
        a1 += __builtin_nontemporal_load(xv + (size_t)(i +  4) * 64 + q);
        a2 += __builtin_nontemporal_load(xv + (size_t)(i +  8) * 64 + q);
        a3 += __builtin_nontemporal_load(xv + (size_t)(i + 12) * 64 + q);
    }
    for (; i < end; i += 4) {
        a0 += __builtin_nontemporal_load(xv + (size_t)i * 64 + q);
    }
    a0 = (a0 + a1) + (a2 + a3);

    // --- cross-team reduction in LDS, then scale + store ---
    __shared__ vf4 s_part[3][64];
    if (r > 0) s_part[r - 1][q] = a0;
    __syncthreads();
    if (r == 0) {
        a0 += s_part[0][q];
        a0 += s_part[1][q];
        a0 += s_part[2][q];
        const float inv = 1.0f / (float)(count > 1 ? count : 1);
        a0 *= inv;
        reinterpret_cast<vf4*>(out)[(size_t)g * 64 + q] = a0;
    }
}

extern "C" void kernel_launch(void* const* d_in, const int* in_sizes, int n_in,
                              void* d_out, int out_size, void* d_ws, size_t ws_size,
                              hipStream_t stream) {
    const float* x     = (const float*)d_in[0];
    const int*   batch = (const int*)d_in[1];
    float*       out   = (float*)d_out;

    const int N = in_sizes[1];        // nodes (1,000,000)
    const int G = out_size / 256;     // graphs (1024)

    meanpool_v5<<<G, 256, 0, stream>>>(x, batch, out, N, G);
}